// Round 4
// baseline (1549.907 us; speedup 1.0000x reference)
//
#include <hip/hip_runtime.h>
#include <math.h>

#define NTOK 16384
#define KD   2048
#define NE   256

constexpr int TM = 16;     // tokens per block
constexpr int BK = 32;     // K chunk
constexpr int SA = 34;     // As row stride (floats)
constexpr int SB = 34;     // Bs row stride (floats)
constexpr int SL = 257;    // Ls row stride (floats)

// Replicates numpy-2.x npyv(SSE3, no-FMA) einsum contraction bitwise:
//   lane l accumulates h ≡ l (mod 4); 16-wide blocks ascending;
//   within block: s = p(m+l) + (p(m+4+l) + (p(m+8+l) + (p(m+12+l) + s)))
//   final: (s0+s1)+(s2+s3)
__global__ __launch_bounds__(256) void gate_kernel(
    const float* __restrict__ hid, const float* __restrict__ wgt,
    float* __restrict__ out, float* __restrict__ cnt, float* __restrict__ prb)
{
    __shared__ float As[TM][SA];
    __shared__ float Bs[NE][SB];
    __shared__ float Ls[TM][SL];
    __shared__ float maxS[TM], sumS[TM], invS[TM];

    const int tid = threadIdx.x;
    const int tx  = tid & 31;       // experts tx*8 .. tx*8+7
    const int ty  = tid >> 5;       // tokens ty*2, ty*2+1
    const int t0  = blockIdx.x * TM;

    float4 acc[2][8];
#pragma unroll
    for (int i = 0; i < 2; ++i)
#pragma unroll
        for (int j = 0; j < 8; ++j) acc[i][j] = make_float4(0.f, 0.f, 0.f, 0.f);

    const int lrow = tid >> 3;        // 0..31
    const int lk   = (tid & 7) * 4;   // 0,4,..,28

    for (int k0 = 0; k0 < KD; k0 += BK) {
        float4 av = make_float4(0.f, 0.f, 0.f, 0.f);
        if (tid < 128)
            av = *(const float4*)(hid + (size_t)(t0 + lrow) * KD + k0 + lk);
        float4 bv[8];
#pragma unroll
        for (int p = 0; p < 8; ++p)
            bv[p] = *(const float4*)(wgt + (size_t)(p * 32 + lrow) * KD + k0 + lk);

        __syncthreads();
        if (tid < 128)
            *(float4*)&As[lrow][lk] = av;
#pragma unroll
        for (int p = 0; p < 8; ++p)
            *(float4*)&Bs[p * 32 + lrow][lk] = bv[p];
        __syncthreads();

#pragma unroll
        for (int kb = 0; kb < BK; kb += 16) {
            float4 a4[2][4];
#pragma unroll
            for (int i = 0; i < 2; ++i)
#pragma unroll
                for (int ss = 0; ss < 4; ++ss)
                    a4[i][ss] = *(const float4*)&As[ty * 2 + i][kb + ss * 4];
#pragma unroll
            for (int j = 0; j < 8; ++j) {
                const float* bp = &Bs[tx * 8 + j][kb];
                const float4 b0 = *(const float4*)(bp);
                const float4 b1 = *(const float4*)(bp + 4);
                const float4 b2 = *(const float4*)(bp + 8);
                const float4 b3 = *(const float4*)(bp + 12);
#pragma unroll
                for (int i = 0; i < 2; ++i) {
                    float4 s = acc[i][j];
                    s.x = __fadd_rn(__fmul_rn(a4[i][0].x, b0.x),
                          __fadd_rn(__fmul_rn(a4[i][1].x, b1.x),
                          __fadd_rn(__fmul_rn(a4[i][2].x, b2.x),
                          __fadd_rn(__fmul_rn(a4[i][3].x, b3.x), s.x))));
                    s.y = __fadd_rn(__fmul_rn(a4[i][0].y, b0.y),
                          __fadd_rn(__fmul_rn(a4[i][1].y, b1.y),
                          __fadd_rn(__fmul_rn(a4[i][2].y, b2.y),
                          __fadd_rn(__fmul_rn(a4[i][3].y, b3.y), s.y))));
                    s.z = __fadd_rn(__fmul_rn(a4[i][0].z, b0.z),
                          __fadd_rn(__fmul_rn(a4[i][1].z, b1.z),
                          __fadd_rn(__fmul_rn(a4[i][2].z, b2.z),
                          __fadd_rn(__fmul_rn(a4[i][3].z, b3.z), s.z))));
                    s.w = __fadd_rn(__fmul_rn(a4[i][0].w, b0.w),
                          __fadd_rn(__fmul_rn(a4[i][1].w, b1.w),
                          __fadd_rn(__fmul_rn(a4[i][2].w, b2.w),
                          __fadd_rn(__fmul_rn(a4[i][3].w, b3.w), s.w))));
                    acc[i][j] = s;
                }
            }
        }
    }

    // ---- final logits: numpy hadd tree (s0+s1)+(s2+s3) ----
#pragma unroll
    for (int i = 0; i < 2; ++i)
#pragma unroll
        for (int j = 0; j < 8; ++j) {
            const float4 s = acc[i][j];
            Ls[ty * 2 + i][tx * 8 + j] =
                __fadd_rn(__fadd_rn(s.x, s.y), __fadd_rn(s.z, s.w));
        }
    if (tid < TM) sumS[tid] = 0.f;
    __syncthreads();

    // ---- per-token top-k (threads 0..15, one token each), fp32 bit-exact ----
    if (tid < TM) {
        const float* lr = &Ls[tid][0];
        float tv[8]; int ti[8];
#pragma unroll
        for (int j = 0; j < 8; ++j) { tv[j] = -1e30f; ti[j] = 0; }
        float rowmax = -1e30f;

        auto ins8 = [&](float v, int idx) {
#pragma unroll
            for (int p = 0; p < 8; ++p) {
                if (v > tv[p]) {
#pragma unroll
                    for (int q = 7; q > p; --q) { tv[q] = tv[q - 1]; ti[q] = ti[q - 1]; }
                    tv[p] = v; ti[p] = idx;
                    break;
                }
            }
        };

#pragma unroll 1
        for (int g = 0; g < 8; ++g) {
            float v0 = -1e30f, v1 = -1e30f, v2 = -1e30f, v3 = -1e30f;
            int   i0 = 0, i1 = 0, i2 = 0, i3 = 0;
            for (int j = 0; j < 32; ++j) {
                const float v = lr[g * 32 + j];
                if (v > v0)      { v3=v2;i3=i2; v2=v1;i2=i1; v1=v0;i1=i0; v0=v;i0=j; }
                else if (v > v1) { v3=v2;i3=i2; v2=v1;i2=i1; v1=v;i1=j; }
                else if (v > v2) { v3=v2;i3=i2; v2=v;i2=j; }
                else if (v > v3) { v3=v;i3=j; }
            }
            rowmax = fmaxf(rowmax, v0);
            // pooled insertion in lax.top_k stable order (g asc, rank asc)
            ins8(v0, g * 32 + i0);
            ins8(v1, g * 32 + i1);
            ins8(v2, g * 32 + i2);
            ins8(v3, g * 32 + i3);
        }

        // numpy pairwise tree for the 8-element sum
        const float s01 = __fadd_rn(tv[0], tv[1]);
        const float s23 = __fadd_rn(tv[2], tv[3]);
        const float s45 = __fadd_rn(tv[4], tv[5]);
        const float s67 = __fadd_rn(tv[6], tv[7]);
        float s = __fadd_rn(__fadd_rn(s01, s23), __fadd_rn(s45, s67));
        s = __fadd_rn(s, 1e-20f);

        const size_t tg = (size_t)(t0 + tid);
#pragma unroll
        for (int j = 0; j < 8; ++j) {
            out[tg * 8 + j]                    = (float)ti[j];
            out[(size_t)NTOK * 8 + tg * 8 + j] = __fdiv_rn(tv[j], s);
            atomicAdd(&cnt[ti[j]], 1.0f);
        }
        maxS[tid] = rowmax;
    }
    __syncthreads();

    // ---- per-token softmax denominator (16 threads per token) ----
    {
        const int t  = tid >> 4;
        const int c0 = (tid & 15) * 16;
        const float m = maxS[t];
        float part = 0.f;
#pragma unroll
        for (int j = 0; j < 16; ++j) part += __expf(Ls[t][c0 + j] - m);
        atomicAdd(&sumS[t], part);
    }
    __syncthreads();
    if (tid < TM) invS[tid] = 1.0f / sumS[tid];
    __syncthreads();

    // ---- per-expert softmax-prob partial sum over the block's tokens ----
    {
        float p = 0.f;
#pragma unroll
        for (int n = 0; n < TM; ++n) p += __expf(Ls[n][tid] - maxS[n]) * invS[n];
        atomicAdd(&prb[tid], p);
    }
}

__global__ void aux_kernel(const float* __restrict__ cnt,
                           const float* __restrict__ prb,
                           float* __restrict__ out)
{
    const int tid = threadIdx.x;
    float v = cnt[tid] * prb[tid];
#pragma unroll
    for (int off = 32; off; off >>= 1) v += __shfl_down(v, off, 64);
    __shared__ float ps[4];
    if ((tid & 63) == 0) ps[tid >> 6] = v;
    __syncthreads();
    if (tid == 0) {
        const float tot = ps[0] + ps[1] + ps[2] + ps[3];
        // aux = alpha * sum_e (count_e/(N*K)) * (P_e/N)
        out[(size_t)NTOK * 8 * 2] = tot * (0.001f / (131072.0f * 16384.0f));
    }
}

extern "C" void kernel_launch(void* const* d_in, const int* in_sizes, int n_in,
                              void* d_out, int out_size, void* d_ws, size_t ws_size,
                              hipStream_t stream)
{
    (void)in_sizes; (void)n_in; (void)out_size; (void)ws_size;
    const float* hid = (const float*)d_in[0];
    const float* wgt = (const float*)d_in[1];
    float* out = (float*)d_out;
    float* cnt = (float*)d_ws;
    float* prb = cnt + NE;

    hipMemsetAsync(d_ws, 0, 2 * NE * sizeof(float), stream);
    gate_kernel<<<NTOK / TM, 256, 0, stream>>>(hid, wgt, out, cnt, prb);
    aux_kernel<<<1, 256, 0, stream>>>(cnt, prb, out);
}

// Round 5
// 545.011 us; speedup vs baseline: 2.8438x; 2.8438x over previous
//
#include <hip/hip_runtime.h>
#include <math.h>

#define NTOK 16384
#define KD   2048
#define NE   256
#define NCHUNK 128            // KD / 16
#define CHUNK_DW 4096         // NE * 16 dwords per 16-K chunk image
#define TM 16                 // tokens per block
#define SL 257                // Ls row stride (floats)

// ---- kernel 0: pre-transform W into chunked, lane-split, slot-swizzled image.
// Bt[c][e][(l ^ ((e>>1)&3))*4 + q] = W[e][16c + 4q + l]
__global__ __launch_bounds__(256) void transform_kernel(
    const float* __restrict__ wgt, float* __restrict__ Bt)
{
    const int c  = blockIdx.x >> 2;
    const int qt = blockIdx.x & 3;
    const int o  = qt * 1024 + threadIdx.x * 4;   // dword offset within chunk
    const int e  = o >> 4;
    const int l  = ((o & 15) >> 2) ^ ((e >> 1) & 3);
    const float* src = wgt + (size_t)e * KD + 16 * c + l;
    float4 v = make_float4(src[0], src[4], src[8], src[12]);   // q = 0..3
    *(float4*)(Bt + (size_t)c * CHUNK_DW + o) = v;
}

typedef __attribute__((address_space(1))) const void GV;
typedef __attribute__((address_space(3))) void LV;
__device__ __forceinline__ void gld_lds16(const float* g, float* l) {
    __builtin_amdgcn_global_load_lds((GV*)g, (LV*)l, 16, 0, 0);
}

// Bit-exact replication of numpy npyv(SSE3,no-FMA) einsum:
//   lane l sums k ≡ l (mod 4); per 16-block: s = p0+(p1+(p2+(p3+s)));
//   final (s0+s1)+(s2+s3).  Lane-chains split across thread-quads.
__global__ __launch_bounds__(256) void gate_kernel(
    const float* __restrict__ hid, const float* __restrict__ Bt,
    float* __restrict__ out, float* __restrict__ cnt, float* __restrict__ prb)
{
    __shared__ union { float bs[2][CHUNK_DW]; float ls[TM][SL]; } sh;
    __shared__ float As[2][TM][16];
    __shared__ float maxS[TM], sumS[TM], invS[TM];

    const int tid  = threadIdx.x;
    const int l    = tid & 3;
    const int eg   = (tid >> 2) & 31;      // experts eg, eg+32, ..., eg+224
    const int tg   = tid >> 7;             // token group 0/1 (8 tokens each)
    const int t0   = blockIdx.x * TM;
    const int lane = tid & 63;
    const int w    = tid >> 6;
    const int swz  = l ^ ((eg >> 1) & 3);  // j-independent slot swizzle

    float acc[8][8];
#pragma unroll
    for (int i = 0; i < 8; ++i)
#pragma unroll
        for (int j = 0; j < 8; ++j) acc[i][j] = 0.f;

    // ---- A staging (16 lanes per wave: one float4 = fixed q, l=0..3) ----
    const bool aact = (lane < 16);
    const int  at   = w * 4 + (lane >> 2);   // token 0..15
    const int  aq   = lane & 3;
    float av[4];

    auto stageA_load = [&](int c) {
        if (aact)
            *(float4*)av = *(const float4*)(hid + (size_t)(t0 + at) * KD + 16 * c + 4 * aq);
    };
    auto stageA_write = [&](int buf) {
        if (aact) {
#pragma unroll
            for (int ll = 0; ll < 4; ++ll)
                As[buf][at][ll * 4 + aq] = av[ll];
        }
    };
    auto stageB = [&](int c, int buf) {
        const float* src = Bt + (size_t)c * CHUNK_DW + tid * 4;
        float* dst = &sh.bs[buf][tid * 4];
#pragma unroll
        for (int s = 0; s < 4; ++s)
            gld_lds16(src + s * 1024, dst + s * 1024);
    };

    stageA_load(0);
    stageB(0, 0);
    stageA_write(0);
    int cur = 0;

#pragma unroll 1
    for (int c = 0; c < NCHUNK; ++c) {
        __syncthreads();                       // cur buffers ready; nxt free
        const int nxt = cur ^ 1;
        if (c + 1 < NCHUNK) { stageA_load(c + 1); stageB(c + 1, nxt); }

        float4 a[8];
#pragma unroll
        for (int tt = 0; tt < 8; ++tt)
            a[tt] = *(const float4*)&As[cur][tg * 8 + tt][l * 4];
#pragma unroll
        for (int j = 0; j < 8; ++j) {
            const float4 b = *(const float4*)&sh.bs[cur][(eg + 32 * j) * 16 + swz * 4];
#pragma unroll
            for (int tt = 0; tt < 8; ++tt) {
                float s = acc[tt][j];
                s = __fadd_rn(__fmul_rn(a[tt].w, b.w), s);   // q=3
                s = __fadd_rn(__fmul_rn(a[tt].z, b.z), s);   // q=2
                s = __fadd_rn(__fmul_rn(a[tt].y, b.y), s);   // q=1
                s = __fadd_rn(__fmul_rn(a[tt].x, b.x), s);   // q=0
                acc[tt][j] = s;
            }
        }
        if (c + 1 < NCHUNK) stageA_write(nxt);
        cur = nxt;
    }

    // ---- combine lane-chains: (s0+s1)+(s2+s3), bitwise-commutative adds ----
    __syncthreads();                           // all waves done reading bs
#pragma unroll
    for (int tt = 0; tt < 8; ++tt)
#pragma unroll
        for (int j = 0; j < 8; ++j) {
            float s = acc[tt][j];
            s = __fadd_rn(s, __shfl_xor(s, 1));
            s = __fadd_rn(s, __shfl_xor(s, 2));
            if (l == 0) sh.ls[tg * 8 + tt][eg + 32 * j] = s;
        }
    if (tid < TM) sumS[tid] = 0.f;
    __syncthreads();

    // ---- per-token top-k (threads 0..15), fp32 bit-exact (round-4 logic) ----
    if (tid < TM) {
        const float* lr = &sh.ls[tid][0];
        float tv[8]; int ti[8];
#pragma unroll
        for (int j = 0; j < 8; ++j) { tv[j] = -1e30f; ti[j] = 0; }
        float rowmax = -1e30f;

        auto ins8 = [&](float v, int idx) {
#pragma unroll
            for (int p = 0; p < 8; ++p) {
                if (v > tv[p]) {
#pragma unroll
                    for (int q = 7; q > p; --q) { tv[q] = tv[q - 1]; ti[q] = ti[q - 1]; }
                    tv[p] = v; ti[p] = idx;
                    break;
                }
            }
        };

#pragma unroll 1
        for (int g = 0; g < 8; ++g) {
            float v0 = -1e30f, v1 = -1e30f, v2 = -1e30f, v3 = -1e30f;
            int   i0 = 0, i1 = 0, i2 = 0, i3 = 0;
            for (int j = 0; j < 32; ++j) {
                const float v = lr[g * 32 + j];
                if (v > v0)      { v3=v2;i3=i2; v2=v1;i2=i1; v1=v0;i1=i0; v0=v;i0=j; }
                else if (v > v1) { v3=v2;i3=i2; v2=v1;i2=i1; v1=v;i1=j; }
                else if (v > v2) { v3=v2;i3=i2; v2=v;i2=j; }
                else if (v > v3) { v3=v;i3=j; }
            }
            rowmax = fmaxf(rowmax, v0);
            ins8(v0, g * 32 + i0);
            ins8(v1, g * 32 + i1);
            ins8(v2, g * 32 + i2);
            ins8(v3, g * 32 + i3);
        }

        const float s01 = __fadd_rn(tv[0], tv[1]);
        const float s23 = __fadd_rn(tv[2], tv[3]);
        const float s45 = __fadd_rn(tv[4], tv[5]);
        const float s67 = __fadd_rn(tv[6], tv[7]);
        float s = __fadd_rn(__fadd_rn(s01, s23), __fadd_rn(s45, s67));
        s = __fadd_rn(s, 1e-20f);

        const size_t tg2 = (size_t)(t0 + tid);
#pragma unroll
        for (int j = 0; j < 8; ++j) {
            out[tg2 * 8 + j]                    = (float)ti[j];
            out[(size_t)NTOK * 8 + tg2 * 8 + j] = __fdiv_rn(tv[j], s);
            atomicAdd(&cnt[ti[j]], 1.0f);
        }
        maxS[tid] = rowmax;
    }
    __syncthreads();

    // ---- per-token softmax denominator (16 threads per token) ----
    {
        const int t  = tid >> 4;
        const int c0 = (tid & 15) * 16;
        const float m = maxS[t];
        float part = 0.f;
#pragma unroll
        for (int j = 0; j < 16; ++j) part += __expf(sh.ls[t][c0 + j] - m);
        atomicAdd(&sumS[t], part);
    }
    __syncthreads();
    if (tid < TM) invS[tid] = 1.0f / sumS[tid];
    __syncthreads();

    // ---- per-expert softmax-prob partial over block tokens ----
    {
        float p = 0.f;
#pragma unroll
        for (int n = 0; n < TM; ++n) p += __expf(sh.ls[n][tid] - maxS[n]) * invS[n];
        atomicAdd(&prb[tid], p);
    }
}

__global__ void aux_kernel(const float* __restrict__ cnt,
                           const float* __restrict__ prb,
                           float* __restrict__ out)
{
    const int tid = threadIdx.x;
    float v = cnt[tid] * prb[tid];
#pragma unroll
    for (int off = 32; off; off >>= 1) v += __shfl_down(v, off, 64);
    __shared__ float ps[4];
    if ((tid & 63) == 0) ps[tid >> 6] = v;
    __syncthreads();
    if (tid == 0) {
        const float tot = ps[0] + ps[1] + ps[2] + ps[3];
        out[(size_t)NTOK * 8 * 2] = tot * (0.001f / (131072.0f * 16384.0f));
    }
}

extern "C" void kernel_launch(void* const* d_in, const int* in_sizes, int n_in,
                              void* d_out, int out_size, void* d_ws, size_t ws_size,
                              hipStream_t stream)
{
    (void)in_sizes; (void)n_in; (void)out_size; (void)ws_size;
    const float* hid = (const float*)d_in[0];
    const float* wgt = (const float*)d_in[1];
    float* out = (float*)d_out;
    float* cnt = (float*)d_ws;             // 256 f
    float* prb = cnt + NE;                 // 256 f
    float* Bt  = prb + NE;                 // 2 MB image (16B-aligned: 2048B offset)

    hipMemsetAsync(d_ws, 0, 2 * NE * sizeof(float), stream);
    transform_kernel<<<512, 256, 0, stream>>>(wgt, Bt);
    gate_kernel<<<NTOK / TM, 256, 0, stream>>>(hid, Bt, out, cnt, prb);
    aux_kernel<<<1, 256, 0, stream>>>(cnt, prb, out);
}